// Round 11
// baseline (318.338 us; speedup 1.0000x reference)
//
#include <hip/hip_runtime.h>
#include <hip/hip_bf16.h>
#include <math.h>

#define Bn 32
#define Sn 512
#define Dn 256
#define Hn 8
#define DHn 32
#define En 64
#define FFn 512
#define Ln 2
#define NCLSn 36
#define BANDR 9
#define NBn 19
#define Mn (Bn * Sn)  // 16384 rows

typedef __attribute__((ext_vector_type(8))) short s8v;
typedef __attribute__((ext_vector_type(4))) float f4v;
typedef __attribute__((ext_vector_type(4))) unsigned short us4;
typedef unsigned short ushortT;

__device__ __forceinline__ ushortT f2b(float f) {
    unsigned u = __float_as_uint(f);
    unsigned r = (u + 0x7FFFu + ((u >> 16) & 1u)) >> 16;
    return (ushortT)r;
}

#define GLDS16(g, l)                                                            \
    __builtin_amdgcn_global_load_lds(                                           \
        (const __attribute__((address_space(1))) void*)(g),                     \
        (__attribute__((address_space(3))) void*)(l), 16, 0, 0)

// ---------------- all weight conversions in one dispatch ----------------
__global__ void k_f2b_all(const float* __restrict__ qkvW, const float* __restrict__ outpW,
                          const float* __restrict__ ff1W, const float* __restrict__ ff2W,
                          const float* __restrict__ gatW,
                          ushortT* __restrict__ qkvWb, ushortT* __restrict__ outpWb,
                          ushortT* __restrict__ ff1Wb, ushortT* __restrict__ ff2Wb,
                          ushortT* __restrict__ gatWb) {
    int bid = blockIdx.x;
    if (bid < 1024) {
        int i4 = bid * 256 + threadIdx.x;
        const float* src; ushortT* dst; int off;
        if (i4 < 98304)       { src = qkvW;  dst = qkvWb;  off = 0; }
        else if (i4 < 131072) { src = outpW; dst = outpWb; off = 98304; }
        else if (i4 < 196608) { src = ff1W;  dst = ff1Wb;  off = 131072; }
        else                  { src = ff2W;  dst = ff2Wb;  off = 196608; }
        int j = (i4 - off) * 4;
        float4 v = *(const float4*)(src + j);
        us4 o = {f2b(v.x), f2b(v.y), f2b(v.z), f2b(v.w)};
        *(us4*)(dst + j) = o;
    } else {
        int i = (bid - 1024) * 256 + threadIdx.x;  // L*65536
        int l = i >> 16, rem = i & 65535;
        int k = rem >> 8, n = rem & 255;
        gatWb[(l << 16) + n * 256 + k] = f2b(gatW[i]);
    }
}

// ---------------- embedding + pos enc  /  band adjacency mask (fused) ----------------
__global__ void k_embed_mask(const int* __restrict__ cat, const float* __restrict__ cnt,
                             const float* __restrict__ e0, const float* __restrict__ e1,
                             const float* __restrict__ e2,
                             const float* __restrict__ cW, const float* __restrict__ cb,
                             const float* __restrict__ pos, float* __restrict__ x,
                             ushortT* __restrict__ xb, unsigned char* __restrict__ maskp) {
    if (blockIdx.x < Mn) {
        int bs = blockIdx.x;
        int d = threadIdx.x;                 // 256
        int b = bs >> 9, s = bs & 511;
        float v;
        if (d < 64)       v = e0[cat[(b * 3 + 0) * Sn + s] * En + d];
        else if (d < 128) v = e1[cat[(b * 3 + 1) * Sn + s] * En + (d - 64)];
        else if (d < 192) v = e2[cat[(b * 3 + 2) * Sn + s] * En + (d - 128)];
        else              v = cnt[b * Sn + s] * cW[d - 192] + cb[d - 192];
        float y = v + pos[s * Dn + d];
        x[(size_t)bs * Dn + d] = y;
        xb[(size_t)bs * Dn + d] = f2b(y);
    } else {
        int idx = (blockIdx.x - Mn) * 256 + threadIdx.x;  // B*S*NB
        if (idx >= Bn * Sn * NBn) return;
        int off = idx % NBn;
        int bs = idx / NBn;
        int b = bs >> 9, i = bs & 511;
        int j = i + off - BANDR;
        unsigned char m = 0;
        if (j >= 0 && j < Sn) {
            int dd = off - BANDR;
            int ad = dd < 0 ? -dd : dd;
            if (ad <= 1) {
                m = 1;
            } else {
                int c = 0;
                for (int f = 0; f < 3; f++)
                    c += (cat[(b * 3 + f) * Sn + i] == cat[(b * 3 + f) * Sn + j]);
                float cat_sim = (float)c / 3.0f;
                float cnt_sim = expf(-fabsf(cnt[b * Sn + i] - cnt[b * Sn + j]) / 100.0f);
                float sim = 0.5f * (cat_sim + cnt_sim);
                m = (sim > 0.6f) ? 1 : 0;
            }
        }
        maskp[idx] = m;
    }
}

// ---------------- bf16 MFMA GEMM (BM=128, BN=128), 1-barrier pipelined ----------------
template <int ACT>
__global__ __launch_bounds__(256) void k_gemm_mfma(const ushortT* __restrict__ A,
                                                   const ushortT* __restrict__ Bt,
                                                   const float* __restrict__ bias,
                                                   ushortT* __restrict__ Cout,
                                                   int M, int N, int K) {
    __shared__ ushortT As[2][128 * 32];
    __shared__ ushortT Bs[2][128 * 32];
    int tid = threadIdx.x;
    int w = tid >> 6, lane = tid & 63;
    int g = lane >> 4, lr = lane & 15;
    int m0 = blockIdx.y * 128, n0 = blockIdx.x * 128;
    int wr = w >> 1, wc = w & 1;
    int NT = K >> 5;
    f4v acc[4][4];
#pragma unroll
    for (int m = 0; m < 4; m++)
#pragma unroll
        for (int n = 0; n < 4; n++) acc[m][n] = (f4v){0.f, 0.f, 0.f, 0.f};

    auto stage = [&](int t, int buf) {
        int k0 = t << 5;
#pragma unroll
        for (int r = 0; r < 2; r++) {
            int e = (tid + r * 256) * 8;
            int row = e >> 5, kk = e & 31;
            GLDS16(A + (size_t)(m0 + row) * K + k0 + kk, &As[buf][e]);
            GLDS16(Bt + (size_t)(n0 + row) * K + k0 + kk, &Bs[buf][e]);
        }
    };

    stage(0, 0);
    __syncthreads();
    for (int t = 0; t < NT; t++) {
        int cur = t & 1;
        if (t + 1 < NT) stage(t + 1, cur ^ 1);  // overlaps compute below
        s8v af[4], bf[4];
#pragma unroll
        for (int m = 0; m < 4; m++)
            af[m] = *(const s8v*)(&As[cur][(wr * 64 + m * 16 + lr) * 32 + g * 8]);
#pragma unroll
        for (int n = 0; n < 4; n++)
            bf[n] = *(const s8v*)(&Bs[cur][(wc * 64 + n * 16 + lr) * 32 + g * 8]);
#pragma unroll
        for (int m = 0; m < 4; m++)
#pragma unroll
            for (int n = 0; n < 4; n++)
                acc[m][n] = __builtin_amdgcn_mfma_f32_16x16x32_bf16(af[m], bf[n], acc[m][n], 0, 0, 0);
        __syncthreads();
    }
#pragma unroll
    for (int m = 0; m < 4; m++) {
#pragma unroll
        for (int n = 0; n < 4; n++) {
            int col = n0 + wc * 64 + n * 16 + lr;
            float bv = bias ? bias[col] : 0.0f;
#pragma unroll
            for (int r = 0; r < 4; r++) {
                int row = m0 + wr * 64 + m * 16 + g * 4 + r;
                float v = acc[m][n][r] + bv;
                if (ACT == 1) v = fmaxf(v, 0.0f);
                Cout[(size_t)row * N + col] = f2b(v);
            }
        }
    }
}

// ---------------- fused row GEMM v2: BM=32 x BN=256, 4 waves, grid 512 ----------------
template <int MODE>
__global__ __launch_bounds__(256) void k_gemm_row(const ushortT* __restrict__ A,
                                                  const ushortT* __restrict__ Bt,
                                                  const float* __restrict__ bias,
                                                  const float* __restrict__ ga,
                                                  float* __restrict__ a1h, float* __restrict__ a2h,
                                                  float* __restrict__ Whout,
                                                  const float* __restrict__ lg,
                                                  const float* __restrict__ lb,
                                                  float* __restrict__ x, ushortT* __restrict__ xb,
                                                  int K) {
    __shared__ ushortT As[2][32 * 32];
    __shared__ ushortT Bs[2][256 * 32];
    __shared__ float red1[32][4], red2[32][4];
    int tid = threadIdx.x;
    int w = tid >> 6, lane = tid & 63;
    int g = lane >> 4, lr = lane & 15;
    int m0 = blockIdx.x * 32;
    int NT = K >> 5;
    f4v acc[2][4];
#pragma unroll
    for (int m = 0; m < 2; m++)
#pragma unroll
        for (int n = 0; n < 4; n++) acc[m][n] = (f4v){0.f, 0.f, 0.f, 0.f};

    auto stage = [&](int t, int buf) {
        int k0 = t << 5;
        if (tid < 128) {
            int e = tid * 8;
            int row = e >> 5, kk = e & 31;
            GLDS16(A + (size_t)(m0 + row) * K + k0 + kk, &As[buf][e]);
        }
#pragma unroll
        for (int r = 0; r < 4; r++) {
            int e = (tid + r * 256) * 8;
            int row = e >> 5, kk = e & 31;
            GLDS16(Bt + (size_t)row * K + k0 + kk, &Bs[buf][e]);
        }
    };

    stage(0, 0);
    __syncthreads();
    for (int t = 0; t < NT; t++) {
        int cur = t & 1;
        if (t + 1 < NT) stage(t + 1, cur ^ 1);
        s8v af[2], bf[4];
#pragma unroll
        for (int m = 0; m < 2; m++)
            af[m] = *(const s8v*)(&As[cur][(m * 16 + lr) * 32 + g * 8]);
#pragma unroll
        for (int n = 0; n < 4; n++)
            bf[n] = *(const s8v*)(&Bs[cur][(w * 64 + n * 16 + lr) * 32 + g * 8]);
#pragma unroll
        for (int m = 0; m < 2; m++)
#pragma unroll
            for (int n = 0; n < 4; n++)
                acc[m][n] = __builtin_amdgcn_mfma_f32_16x16x32_bf16(af[m], bf[n], acc[m][n], 0, 0, 0);
        __syncthreads();
    }

    int cn[4];
#pragma unroll
    for (int n = 0; n < 4; n++) cn[n] = w * 64 + n * 16 + lr;

    if constexpr (MODE == 0) {
        float a1v[4], a2v[4];
#pragma unroll
        for (int n = 0; n < 4; n++) { a1v[n] = ga[cn[n]]; a2v[n] = ga[Dn + cn[n]]; }
#pragma unroll
        for (int m = 0; m < 2; m++)
#pragma unroll
            for (int r = 0; r < 4; r++) {
                int rowl = m * 16 + g * 4 + r;
                float p1 = 0.f, p2 = 0.f;
#pragma unroll
                for (int n = 0; n < 4; n++) {
                    float v = acc[m][n][r];
                    Whout[(size_t)(m0 + rowl) * Dn + cn[n]] = v;
                    p1 += v * a1v[n];
                    p2 += v * a2v[n];
                }
                p1 += __shfl_xor(p1, 1); p2 += __shfl_xor(p2, 1);
                p1 += __shfl_xor(p1, 2); p2 += __shfl_xor(p2, 2);
                p1 += __shfl_xor(p1, 4); p2 += __shfl_xor(p2, 4);
                p1 += __shfl_xor(p1, 8); p2 += __shfl_xor(p2, 8);
                if (lr == 0) { red1[rowl][w] = p1; red2[rowl][w] = p2; }
            }
        __syncthreads();
        if (tid < 32) {
            float t1 = red1[tid][0] + red1[tid][1] + red1[tid][2] + red1[tid][3];
            float t2 = red2[tid][0] + red2[tid][1] + red2[tid][2] + red2[tid][3];
            a1h[m0 + tid] = t1;
            a2h[m0 + tid] = t2;
        }
    } else {
        float bv[4], lgv[4], lbv[4];
#pragma unroll
        for (int n = 0; n < 4; n++) { bv[n] = bias[cn[n]]; lgv[n] = lg[cn[n]]; lbv[n] = lb[cn[n]]; }
#pragma unroll
        for (int m = 0; m < 2; m++)
#pragma unroll
            for (int r = 0; r < 4; r++) {
                int rowl = m * 16 + g * 4 + r;
                float s1 = 0.f, s2 = 0.f;
#pragma unroll
                for (int n = 0; n < 4; n++) {
                    float y = acc[m][n][r] + bv[n] + x[(size_t)(m0 + rowl) * Dn + cn[n]];
                    acc[m][n][r] = y;
                    s1 += y;
                    s2 += y * y;
                }
                s1 += __shfl_xor(s1, 1); s2 += __shfl_xor(s2, 1);
                s1 += __shfl_xor(s1, 2); s2 += __shfl_xor(s2, 2);
                s1 += __shfl_xor(s1, 4); s2 += __shfl_xor(s2, 4);
                s1 += __shfl_xor(s1, 8); s2 += __shfl_xor(s2, 8);
                if (lr == 0) { red1[rowl][w] = s1; red2[rowl][w] = s2; }
            }
        __syncthreads();
#pragma unroll
        for (int m = 0; m < 2; m++)
#pragma unroll
            for (int r = 0; r < 4; r++) {
                int rowl = m * 16 + g * 4 + r;
                float S1 = red1[rowl][0] + red1[rowl][1] + red1[rowl][2] + red1[rowl][3];
                float S2 = red2[rowl][0] + red2[rowl][1] + red2[rowl][2] + red2[rowl][3];
                float mean = S1 * (1.0f / Dn);
                float var = S2 * (1.0f / Dn) - mean * mean;
                float rs = rsqrtf(var + 1e-5f);
#pragma unroll
                for (int n = 0; n < 4; n++) {
                    float o = lgv[n] * (acc[m][n][r] - mean) * rs + lbv[n];
                    size_t idx = (size_t)(m0 + rowl) * Dn + cn[n];
                    x[idx] = o;
                    xb[idx] = f2b(o);
                }
            }
    }
}

// ---------------- GAT band softmax + ELU + residual + LN (wave per row) ----------------
__global__ __launch_bounds__(256) void k_gat_attn_ln(const float* __restrict__ Wh,
                                                     const float* __restrict__ a1h,
                                                     const float* __restrict__ a2h,
                                                     const unsigned char* __restrict__ mask,
                                                     const float* __restrict__ lg,
                                                     const float* __restrict__ lb,
                                                     float* __restrict__ x,
                                                     ushortT* __restrict__ xb) {
    int w = threadIdx.x >> 6, l = threadIdx.x & 63;
    int bs = blockIdx.x * 4 + w;
    int b = bs >> 9, i = bs & 511;
    float e = -1e30f;
    int j = i + l - BANDR;
    if (l < NBn && j >= 0 && j < Sn && mask[bs * NBn + l])
        e = a1h[bs] + a2h[(b << 9) + j];
    float mx = e;
#pragma unroll
    for (int o = 32; o; o >>= 1) mx = fmaxf(mx, __shfl_xor(mx, o));
    float p = (e > -1e29f) ? __expf(e - mx) : 0.0f;
    float sum = p;
#pragma unroll
    for (int o = 32; o; o >>= 1) sum += __shfl_xor(sum, o);
    p *= (1.0f / sum);
    int c4 = l * 4;
    const float* whb = Wh + (size_t)(b << 9) * Dn + c4;
    float gx = 0.f, gy = 0.f, gz = 0.f, gw = 0.f;
#pragma unroll
    for (int o = 0; o < NBn; o++) {
        float wo = __shfl(p, o);
        int jo = i + o - BANDR;
        jo = jo < 0 ? 0 : (jo > Sn - 1 ? Sn - 1 : jo);
        float4 v = *(const float4*)(whb + (size_t)jo * Dn);
        gx += wo * v.x; gy += wo * v.y; gz += wo * v.z; gw += wo * v.w;
    }
    gx = gx > 0.f ? gx : expm1f(gx);
    gy = gy > 0.f ? gy : expm1f(gy);
    gz = gz > 0.f ? gz : expm1f(gz);
    gw = gw > 0.f ? gw : expm1f(gw);
    float4 xv = *(const float4*)(x + (size_t)bs * Dn + c4);
    float y0 = xv.x + gx, y1 = xv.y + gy, y2 = xv.z + gz, y3 = xv.w + gw;
    float s1 = y0 + y1 + y2 + y3;
    float s2 = y0 * y0 + y1 * y1 + y2 * y2 + y3 * y3;
#pragma unroll
    for (int o = 32; o; o >>= 1) {
        s1 += __shfl_xor(s1, o);
        s2 += __shfl_xor(s2, o);
    }
    float mean = s1 * (1.0f / Dn);
    float var = s2 * (1.0f / Dn) - mean * mean;
    float r = rsqrtf(var + 1e-5f);
    float4 lgv = *(const float4*)(lg + c4);
    float4 lbv = *(const float4*)(lb + c4);
    float o0 = lgv.x * (y0 - mean) * r + lbv.x;
    float o1 = lgv.y * (y1 - mean) * r + lbv.y;
    float o2 = lgv.z * (y2 - mean) * r + lbv.z;
    float o3 = lgv.w * (y3 - mean) * r + lbv.w;
    *(float4*)(x + (size_t)bs * Dn + c4) = make_float4(o0, o1, o2, o3);
    us4 ob = {f2b(o0), f2b(o1), f2b(o2), f2b(o3)};
    *(us4*)(xb + (size_t)bs * Dn + c4) = ob;
}

// ---------------- MFMA flash attention v6: 4-way q-split, single-buffered, TLP ----------------
// Block = (b, h, q-quarter): 4 waves x 32 q-rows, grid 1024 (~4 blocks/CU).
// Single K/V LDS buffer (30 KB total); staging of tile t+1 issued right after
// fragment reads of tile t (barrier-separated), so DMA overlaps the compute phase.
// Cross-block TLP hides the per-tile barrier drains.
__global__ __launch_bounds__(256) void k_attn_mfma(const ushortT* __restrict__ qkv,
                                                   ushortT* __restrict__ ob) {
    __shared__ ushortT Ks[64 * 32];
    __shared__ ushortT Vt[32 * 64];
    __shared__ ushortT Ps[4][2][16 * 72];  // [wave][pipeline buf][16 rows x 72]
    int tid = threadIdx.x;
    int w = tid >> 6, lane = tid & 63;
    int g = lane >> 4, lr = lane & 15;
    int blk = blockIdx.x;
    int qq = blk & 3, h = (blk >> 2) & 7, b = blk >> 5;
    const ushortT* base = qkv + (size_t)b * Sn * 768;
    const ushortT* kbase = base + 256 + h * 32;
    const ushortT* vbase = base + 512 + h * 32;

    // K staging source swizzle (chunk ^= row2&7), linear LDS dest = tid*16B
    int krow2 = tid >> 3;
    int kc = (tid & 7) ^ (krow2 & 7);
    int kkv = krow2 * 2 + (kc >> 2);
    int kdd = (kc & 3) * 8;
    int vd0 = w * 8;

    int q0 = qq * 128 + w * 32;
    s8v qf[2];
#pragma unroll
    for (int m = 0; m < 2; m++)
        qf[m] = *(const s8v*)(base + (size_t)(q0 + m * 16 + lr) * 768 + h * 32 + g * 8);

    f4v o[2][2];
    float rl[2][4];
#pragma unroll
    for (int m = 0; m < 2; m++) {
        o[m][0] = (f4v){0.f, 0.f, 0.f, 0.f};
        o[m][1] = (f4v){0.f, 0.f, 0.f, 0.f};
#pragma unroll
        for (int r = 0; r < 4; r++) rl[m][r] = 0.f;
    }
    const float scale = 0.17677669529663687f;  // 1/sqrt(32)

    // prologue: stage tile 0
    {
        GLDS16(kbase + (size_t)kkv * 768 + kdd, &Ks[tid * 8]);
        us4 v0 = *(const us4*)(vbase + (size_t)lane * 768 + vd0);
        us4 v1 = *(const us4*)(vbase + (size_t)lane * 768 + vd0 + 4);
#pragma unroll
        for (int jj = 0; jj < 4; jj++) {
            int d = vd0 + jj;
            Vt[d * 64 + (lane ^ ((d & 7) << 3))] = v0[jj];
            int d2 = d + 4;
            Vt[d2 * 64 + (lane ^ ((d2 & 7) << 3))] = v1[jj];
        }
    }
    __syncthreads();  // barrier A: tile-0 staging complete (drains GLDS + ds_writes)

    for (int kt = 0; kt < 8; kt++) {
        // fragment reads of tile kt from the single buffers
        s8v kf[4];
#pragma unroll
        for (int n = 0; n < 4; n++) {
            int row2 = n * 8 + (lr >> 1);
            int cc = (((lr & 1) << 2) + g) ^ (row2 & 7);
            kf[n] = *(const s8v*)(&Ks[row2 * 64 + cc * 8]);
        }
        s8v vf[2][2];
#pragma unroll
        for (int cd = 0; cd < 2; cd++)
#pragma unroll
            for (int c2 = 0; c2 < 2; c2++) {
                int d = cd * 16 + lr;
                vf[cd][c2] = *(const s8v*)(&Vt[d * 64 + ((c2 * 32 + g * 8) ^ ((d & 7) << 3))]);
            }
        __syncthreads();  // barrier B: all waves' LDS reads done -> buffers free
        us4 v0, v1;
        if (kt < 7) {
            // issue next-tile staging into the (now free) single buffers;
            // DMA + global loads overlap the compute below
            GLDS16(kbase + (size_t)((kt + 1) * 64 + kkv) * 768 + kdd, &Ks[tid * 8]);
            v0 = *(const us4*)(vbase + (size_t)((kt + 1) * 64 + lane) * 768 + vd0);
            v1 = *(const us4*)(vbase + (size_t)((kt + 1) * 64 + lane) * 768 + vd0 + 4);
        }
        // pipelined m-loop: QK(m) -> exp(m) -> PV(m-1) -> store(m); Ps per-wave
#pragma unroll
        for (int m = 0; m < 2; m++) {
            f4v s[4];
#pragma unroll
            for (int n = 0; n < 4; n++) {
                f4v z = (f4v){0.f, 0.f, 0.f, 0.f};
                s[n] = __builtin_amdgcn_mfma_f32_16x16x32_bf16(qf[m], kf[n], z, 0, 0, 0);
            }
            float pr[4][4];
#pragma unroll
            for (int r = 0; r < 4; r++) {
                pr[0][r] = __expf(fminf(s[0][r] * scale, 60.f));
                pr[1][r] = __expf(fminf(s[1][r] * scale, 60.f));
                pr[2][r] = __expf(fminf(s[2][r] * scale, 60.f));
                pr[3][r] = __expf(fminf(s[3][r] * scale, 60.f));
                rl[m][r] += (pr[0][r] + pr[1][r]) + (pr[2][r] + pr[3][r]);
            }
            if (m > 0) {
                s8v pf0 = *(const s8v*)(&Ps[w][0][lr * 72 + g * 8]);
                s8v pf1 = *(const s8v*)(&Ps[w][0][lr * 72 + 32 + g * 8]);
                o[0][0] = __builtin_amdgcn_mfma_f32_16x16x32_bf16(pf0, vf[0][0], o[0][0], 0, 0, 0);
                o[0][0] = __builtin_amdgcn_mfma_f32_16x16x32_bf16(pf1, vf[0][1], o[0][0], 0, 0, 0);
                o[0][1] = __builtin_amdgcn_mfma_f32_16x16x32_bf16(pf0, vf[1][0], o[0][1], 0, 0, 0);
                o[0][1] = __builtin_amdgcn_mfma_f32_16x16x32_bf16(pf1, vf[1][1], o[0][1], 0, 0, 0);
            }
            int sb = m & 1;
#pragma unroll
            for (int r = 0; r < 4; r++) {
                int rr = g * 4 + r;
                Ps[w][sb][rr * 72 + lr]      = f2b(pr[0][r]);
                Ps[w][sb][rr * 72 + 16 + lr] = f2b(pr[1][r]);
                Ps[w][sb][rr * 72 + 32 + lr] = f2b(pr[2][r]);
                Ps[w][sb][rr * 72 + 48 + lr] = f2b(pr[3][r]);
            }
        }
        // drain: PV(1)
        {
            s8v pf0 = *(const s8v*)(&Ps[w][1][lr * 72 + g * 8]);
            s8v pf1 = *(const s8v*)(&Ps[w][1][lr * 72 + 32 + g * 8]);
            o[1][0] = __builtin_amdgcn_mfma_f32_16x16x32_bf16(pf0, vf[0][0], o[1][0], 0, 0, 0);
            o[1][0] = __builtin_amdgcn_mfma_f32_16x16x32_bf16(pf1, vf[0][1], o[1][0], 0, 0, 0);
            o[1][1] = __builtin_amdgcn_mfma_f32_16x16x32_bf16(pf0, vf[1][0], o[1][1], 0, 0, 0);
            o[1][1] = __builtin_amdgcn_mfma_f32_16x16x32_bf16(pf1, vf[1][1], o[1][1], 0, 0, 0);
        }
        if (kt < 7) {
            // write-late V transpose into the single buffer (swizzled)
#pragma unroll
            for (int jj = 0; jj < 4; jj++) {
                int d = vd0 + jj;
                Vt[d * 64 + (lane ^ ((d & 7) << 3))] = v0[jj];
                int d2 = d + 4;
                Vt[d2 * 64 + (lane ^ ((d2 & 7) << 3))] = v1[jj];
            }
        }
        __syncthreads();  // barrier A: staging of tile kt+1 complete
    }
    // epilogue
#pragma unroll
    for (int m = 0; m < 2; m++) {
#pragma unroll
        for (int r = 0; r < 4; r++) {
            float t = rl[m][r];
            t += __shfl_xor(t, 1);
            t += __shfl_xor(t, 2);
            t += __shfl_xor(t, 4);
            t += __shfl_xor(t, 8);
            float inv = 1.0f / t;
            int qr = q0 + m * 16 + g * 4 + r;
            size_t obase = ((size_t)(b * Sn + qr)) * Dn + h * 32;
            ob[obase + lr] = f2b(o[m][0][r] * inv);
            ob[obase + 16 + lr] = f2b(o[m][1][r] * inv);
        }
    }
}

// ---------------- fused mean-pool + classifier ----------------
__global__ void k_pool_cls(const float* __restrict__ x, const float* __restrict__ w1,
                           const float* __restrict__ b1, const float* __restrict__ w2,
                           const float* __restrict__ b2, float* __restrict__ out) {
    int b = blockIdx.x;
    int t = threadIdx.x;  // 256
    __shared__ float pooled[Dn];
    __shared__ float hbuf[128];
    float s = 0.f;
    const float* xp = x + (size_t)(b << 9) * Dn + t;
    for (int sx = 0; sx < Sn; sx++) s += xp[(size_t)sx * Dn];
    pooled[t] = s * (1.0f / Sn);
    __syncthreads();
    if (t < 128) {
        float a = b1[t];
        for (int k = 0; k < Dn; k++) a += pooled[k] * w1[t * Dn + k];
        hbuf[t] = fmaxf(a, 0.0f);
    }
    __syncthreads();
    if (t < NCLSn) {
        float a2 = b2[t];
        for (int k = 0; k < 128; k++) a2 += hbuf[k] * w2[t * 128 + k];
        out[b * NCLSn + t] = a2;
    }
}

extern "C" void kernel_launch(void* const* d_in, const int* in_sizes, int n_in,
                              void* d_out, int out_size, void* d_ws, size_t ws_size,
                              hipStream_t stream) {
    const int* cat = (const int*)d_in[0];
    const float* cnt = (const float*)d_in[1];
    const float* emb0 = (const float*)d_in[2];
    const float* emb1 = (const float*)d_in[3];
    const float* emb2 = (const float*)d_in[4];
    const float* cnt_W = (const float*)d_in[5];
    const float* cnt_b = (const float*)d_in[6];
    const float* pos_enc = (const float*)d_in[7];
    const float* gat_W = (const float*)d_in[8];
    const float* gat_a = (const float*)d_in[9];
    const float* qkv_W = (const float*)d_in[10];
    const float* qkv_b = (const float*)d_in[11];
    const float* outp_W = (const float*)d_in[12];
    const float* outp_b = (const float*)d_in[13];
    const float* ff1_W = (const float*)d_in[14];
    const float* ff1_b = (const float*)d_in[15];
    const float* ff2_W = (const float*)d_in[16];
    const float* ff2_b = (const float*)d_in[17];
    const float* ln_g = (const float*)d_in[18];
    const float* ln_b = (const float*)d_in[19];
    const float* cls1_W = (const float*)d_in[20];
    const float* cls1_b = (const float*)d_in[21];
    const float* cls2_W = (const float*)d_in[22];
    const float* cls2_b = (const float*)d_in[23];
    float* out = (float*)d_out;

    // workspace layout
    char* wp = (char*)d_ws;
    float* x = (float*)wp;        wp += (size_t)Mn * Dn * 4;
    float* tmpf = (float*)wp;     wp += (size_t)Mn * Dn * 4;
    ushortT* xb = (ushortT*)wp;   wp += (size_t)Mn * Dn * 2;
    ushortT* qkvb = (ushortT*)wp; wp += (size_t)Mn * 3 * Dn * 2;
    ushortT* ffb = qkvb;  // alias: qkv dead before ff1 writes
    ushortT* obb = (ushortT*)wp;  wp += (size_t)Mn * Dn * 2;
    float* a1h = (float*)wp;      wp += (size_t)Mn * 4;
    float* a2h = (float*)wp;      wp += (size_t)Mn * 4;
    unsigned char* mask = (unsigned char*)wp; wp += (size_t)Mn * NBn;
    ushortT* gatWb = (ushortT*)wp;  wp += (size_t)Ln * Dn * Dn * 2;
    ushortT* qkvWb = (ushortT*)wp;  wp += (size_t)Ln * 3 * Dn * Dn * 2;
    ushortT* outpWb = (ushortT*)wp; wp += (size_t)Ln * Dn * Dn * 2;
    ushortT* ff1Wb = (ushortT*)wp;  wp += (size_t)Ln * FFn * Dn * 2;
    ushortT* ff2Wb = (ushortT*)wp;  wp += (size_t)Ln * Dn * FFn * 2;

    k_f2b_all<<<1536, 256, 0, stream>>>(qkv_W, outp_W, ff1_W, ff2_W, gat_W,
                                        qkvWb, outpWb, ff1Wb, ff2Wb, gatWb);
    k_embed_mask<<<Mn + 1216, 256, 0, stream>>>(cat, cnt, emb0, emb1, emb2, cnt_W, cnt_b,
                                                pos_enc, x, xb, mask);

    for (int l = 0; l < Ln; l++) {
        // GAT: Wh = x @ gat_W[l] fused with score dots -> tmpf, a1h, a2h
        k_gemm_row<0><<<Mn / 32, 256, 0, stream>>>(
            xb, gatWb + (size_t)l * Dn * Dn, nullptr,
            gat_a + (size_t)l * 2 * Dn, a1h, a2h, tmpf,
            nullptr, nullptr, nullptr, nullptr, Dn);
        k_gat_attn_ln<<<Mn / 4, 256, 0, stream>>>(tmpf, a1h, a2h, mask,
                                                  ln_g + (l * 3 + 0) * Dn, ln_b + (l * 3 + 0) * Dn, x, xb);
        // MHA
        k_gemm_mfma<0><<<dim3(3 * Dn / 128, Mn / 128), 256, 0, stream>>>(
            xb, qkvWb + (size_t)l * 3 * Dn * Dn, qkv_b + l * 3 * Dn, qkvb, Mn, 3 * Dn, Dn);
        k_attn_mfma<<<Bn * Hn * 4, 256, 0, stream>>>(qkvb, obb);
        // out-proj fused with residual + LN
        k_gemm_row<1><<<Mn / 32, 256, 0, stream>>>(
            obb, outpWb + (size_t)l * Dn * Dn, outp_b + l * Dn,
            nullptr, nullptr, nullptr, nullptr,
            ln_g + (l * 3 + 1) * Dn, ln_b + (l * 3 + 1) * Dn, x, xb, Dn);
        // FFN
        k_gemm_mfma<1><<<dim3(FFn / 128, Mn / 128), 256, 0, stream>>>(
            xb, ff1Wb + (size_t)l * FFn * Dn, ff1_b + l * FFn, ffb, Mn, FFn, Dn);
        k_gemm_row<1><<<Mn / 32, 256, 0, stream>>>(
            ffb, ff2Wb + (size_t)l * Dn * FFn, ff2_b + l * Dn,
            nullptr, nullptr, nullptr, nullptr,
            ln_g + (l * 3 + 2) * Dn, ln_b + (l * 3 + 2) * Dn, x, xb, FFn);
    }

    k_pool_cls<<<Bn, 256, 0, stream>>>(x, cls1_W, cls1_b, cls2_W, cls2_b, out);
}

// Round 12
// 302.682 us; speedup vs baseline: 1.0517x; 1.0517x over previous
//
#include <hip/hip_runtime.h>
#include <hip/hip_bf16.h>
#include <math.h>

#define Bn 32
#define Sn 512
#define Dn 256
#define Hn 8
#define DHn 32
#define En 64
#define FFn 512
#define Ln 2
#define NCLSn 36
#define BANDR 9
#define NBn 19
#define Mn (Bn * Sn)  // 16384 rows

typedef __attribute__((ext_vector_type(8))) short s8v;
typedef __attribute__((ext_vector_type(4))) float f4v;
typedef __attribute__((ext_vector_type(4))) unsigned short us4;
typedef unsigned short ushortT;

__device__ __forceinline__ ushortT f2b(float f) {
    unsigned u = __float_as_uint(f);
    unsigned r = (u + 0x7FFFu + ((u >> 16) & 1u)) >> 16;
    return (ushortT)r;
}

#define GLDS16(g, l)                                                            \
    __builtin_amdgcn_global_load_lds(                                           \
        (const __attribute__((address_space(1))) void*)(g),                     \
        (__attribute__((address_space(3))) void*)(l), 16, 0, 0)

// ---------------- all weight conversions in one dispatch ----------------
__global__ void k_f2b_all(const float* __restrict__ qkvW, const float* __restrict__ outpW,
                          const float* __restrict__ ff1W, const float* __restrict__ ff2W,
                          const float* __restrict__ gatW,
                          ushortT* __restrict__ qkvWb, ushortT* __restrict__ outpWb,
                          ushortT* __restrict__ ff1Wb, ushortT* __restrict__ ff2Wb,
                          ushortT* __restrict__ gatWb) {
    int bid = blockIdx.x;
    if (bid < 1024) {
        int i4 = bid * 256 + threadIdx.x;
        const float* src; ushortT* dst; int off;
        if (i4 < 98304)       { src = qkvW;  dst = qkvWb;  off = 0; }
        else if (i4 < 131072) { src = outpW; dst = outpWb; off = 98304; }
        else if (i4 < 196608) { src = ff1W;  dst = ff1Wb;  off = 131072; }
        else                  { src = ff2W;  dst = ff2Wb;  off = 196608; }
        int j = (i4 - off) * 4;
        float4 v = *(const float4*)(src + j);
        us4 o = {f2b(v.x), f2b(v.y), f2b(v.z), f2b(v.w)};
        *(us4*)(dst + j) = o;
    } else {
        int i = (bid - 1024) * 256 + threadIdx.x;  // L*65536
        int l = i >> 16, rem = i & 65535;
        int k = rem >> 8, n = rem & 255;
        gatWb[(l << 16) + n * 256 + k] = f2b(gatW[i]);
    }
}

// ---------------- embedding + pos enc  /  band adjacency mask (fused) ----------------
__global__ void k_embed_mask(const int* __restrict__ cat, const float* __restrict__ cnt,
                             const float* __restrict__ e0, const float* __restrict__ e1,
                             const float* __restrict__ e2,
                             const float* __restrict__ cW, const float* __restrict__ cb,
                             const float* __restrict__ pos, float* __restrict__ x,
                             ushortT* __restrict__ xb, unsigned char* __restrict__ maskp) {
    if (blockIdx.x < Mn) {
        int bs = blockIdx.x;
        int d = threadIdx.x;                 // 256
        int b = bs >> 9, s = bs & 511;
        float v;
        if (d < 64)       v = e0[cat[(b * 3 + 0) * Sn + s] * En + d];
        else if (d < 128) v = e1[cat[(b * 3 + 1) * Sn + s] * En + (d - 64)];
        else if (d < 192) v = e2[cat[(b * 3 + 2) * Sn + s] * En + (d - 128)];
        else              v = cnt[b * Sn + s] * cW[d - 192] + cb[d - 192];
        float y = v + pos[s * Dn + d];
        x[(size_t)bs * Dn + d] = y;
        xb[(size_t)bs * Dn + d] = f2b(y);
    } else {
        int idx = (blockIdx.x - Mn) * 256 + threadIdx.x;  // B*S*NB
        if (idx >= Bn * Sn * NBn) return;
        int off = idx % NBn;
        int bs = idx / NBn;
        int b = bs >> 9, i = bs & 511;
        int j = i + off - BANDR;
        unsigned char m = 0;
        if (j >= 0 && j < Sn) {
            int dd = off - BANDR;
            int ad = dd < 0 ? -dd : dd;
            if (ad <= 1) {
                m = 1;
            } else {
                int c = 0;
                for (int f = 0; f < 3; f++)
                    c += (cat[(b * 3 + f) * Sn + i] == cat[(b * 3 + f) * Sn + j]);
                float cat_sim = (float)c / 3.0f;
                float cnt_sim = expf(-fabsf(cnt[b * Sn + i] - cnt[b * Sn + j]) / 100.0f);
                float sim = 0.5f * (cat_sim + cnt_sim);
                m = (sim > 0.6f) ? 1 : 0;
            }
        }
        maskp[idx] = m;
    }
}

// ---------------- bf16 MFMA GEMM (BM=128, BN=128), 1-barrier pipelined ----------------
template <int ACT>
__global__ __launch_bounds__(256) void k_gemm_mfma(const ushortT* __restrict__ A,
                                                   const ushortT* __restrict__ Bt,
                                                   const float* __restrict__ bias,
                                                   ushortT* __restrict__ Cout,
                                                   int M, int N, int K) {
    __shared__ ushortT As[2][128 * 32];
    __shared__ ushortT Bs[2][128 * 32];
    int tid = threadIdx.x;
    int w = tid >> 6, lane = tid & 63;
    int g = lane >> 4, lr = lane & 15;
    int m0 = blockIdx.y * 128, n0 = blockIdx.x * 128;
    int wr = w >> 1, wc = w & 1;
    int NT = K >> 5;
    f4v acc[4][4];
#pragma unroll
    for (int m = 0; m < 4; m++)
#pragma unroll
        for (int n = 0; n < 4; n++) acc[m][n] = (f4v){0.f, 0.f, 0.f, 0.f};

    auto stage = [&](int t, int buf) {
        int k0 = t << 5;
#pragma unroll
        for (int r = 0; r < 2; r++) {
            int e = (tid + r * 256) * 8;
            int row = e >> 5, kk = e & 31;
            GLDS16(A + (size_t)(m0 + row) * K + k0 + kk, &As[buf][e]);
            GLDS16(Bt + (size_t)(n0 + row) * K + k0 + kk, &Bs[buf][e]);
        }
    };

    stage(0, 0);
    __syncthreads();
    for (int t = 0; t < NT; t++) {
        int cur = t & 1;
        if (t + 1 < NT) stage(t + 1, cur ^ 1);  // overlaps compute below
        s8v af[4], bf[4];
#pragma unroll
        for (int m = 0; m < 4; m++)
            af[m] = *(const s8v*)(&As[cur][(wr * 64 + m * 16 + lr) * 32 + g * 8]);
#pragma unroll
        for (int n = 0; n < 4; n++)
            bf[n] = *(const s8v*)(&Bs[cur][(wc * 64 + n * 16 + lr) * 32 + g * 8]);
#pragma unroll
        for (int m = 0; m < 4; m++)
#pragma unroll
            for (int n = 0; n < 4; n++)
                acc[m][n] = __builtin_amdgcn_mfma_f32_16x16x32_bf16(af[m], bf[n], acc[m][n], 0, 0, 0);
        __syncthreads();
    }
#pragma unroll
    for (int m = 0; m < 4; m++) {
#pragma unroll
        for (int n = 0; n < 4; n++) {
            int col = n0 + wc * 64 + n * 16 + lr;
            float bv = bias ? bias[col] : 0.0f;
#pragma unroll
            for (int r = 0; r < 4; r++) {
                int row = m0 + wr * 64 + m * 16 + g * 4 + r;
                float v = acc[m][n][r] + bv;
                if (ACT == 1) v = fmaxf(v, 0.0f);
                Cout[(size_t)row * N + col] = f2b(v);
            }
        }
    }
}

// ---------------- fused row GEMM v3: BM=32 x BN=256, BK=64, XOR-swizzled LDS ----------------
// 4 waves, grid 512. Half the K-steps (4 for K=256) -> half the barrier vmcnt drains.
// LDS rows are 128B so fragment reads XOR-swizzle the 16B chunk with (row&7);
// the same permutation is applied to the GLDS *source* (LDS dest stays linear).
// MODE 0: C = A @ Bt^T; writes Whout fp32 + a1h/a2h dots. MODE 1: LN(y+x) epilogue.
template <int MODE>
__global__ __launch_bounds__(256) void k_gemm_row(const ushortT* __restrict__ A,
                                                  const ushortT* __restrict__ Bt,
                                                  const float* __restrict__ bias,
                                                  const float* __restrict__ ga,
                                                  float* __restrict__ a1h, float* __restrict__ a2h,
                                                  float* __restrict__ Whout,
                                                  const float* __restrict__ lg,
                                                  const float* __restrict__ lb,
                                                  float* __restrict__ x, ushortT* __restrict__ xb,
                                                  int K) {
    extern __shared__ ushortT smem[];      // As[2][2048] + Bs[2][16384] = 73728 B
    ushortT* As0 = smem;                   // 2 x 2048
    ushortT* Bs0 = smem + 4096;            // 2 x 16384
    __shared__ float red1[32][4], red2[32][4];
    int tid = threadIdx.x;
    int w = tid >> 6, lane = tid & 63;
    int g = lane >> 4, lr = lane & 15;
    int m0 = blockIdx.x * 32;
    int NT = K >> 6;
    f4v acc[2][4];
#pragma unroll
    for (int m = 0; m < 2; m++)
#pragma unroll
        for (int n = 0; n < 4; n++) acc[m][n] = (f4v){0.f, 0.f, 0.f, 0.f};

    auto stage = [&](int t, int buf) {
        int k0 = t << 6;
        {   // A tile 32x64: 1 GLDS16/thread, source chunk pre-swizzled
            int row = tid >> 3;
            int kk = ((tid & 7) ^ (row & 7)) * 8;
            GLDS16(A + (size_t)(m0 + row) * K + k0 + kk, As0 + buf * 2048 + tid * 8);
        }
#pragma unroll
        for (int r = 0; r < 8; r++) {  // B tile 256x64: 8 GLDS16/thread
            int e = (tid + r * 256) * 8;
            int row = e >> 6;
            int c = (e >> 3) & 7;
            int kk = (c ^ (row & 7)) * 8;
            GLDS16(Bt + (size_t)row * K + k0 + kk, Bs0 + buf * 16384 + e);
        }
    };

    stage(0, 0);
    __syncthreads();
    for (int t = 0; t < NT; t++) {
        int cur = t & 1;
        if (t + 1 < NT) stage(t + 1, cur ^ 1);  // DMA overlaps compute below
        s8v af[2][2], bf[2][4];
#pragma unroll
        for (int ks = 0; ks < 2; ks++) {
#pragma unroll
            for (int m = 0; m < 2; m++) {
                int row = m * 16 + lr;
                int c = (ks * 4 + g) ^ (row & 7);
                af[ks][m] = *(const s8v*)(As0 + cur * 2048 + row * 64 + c * 8);
            }
#pragma unroll
            for (int n = 0; n < 4; n++) {
                int row = w * 64 + n * 16 + lr;
                int c = (ks * 4 + g) ^ (row & 7);
                bf[ks][n] = *(const s8v*)(Bs0 + cur * 16384 + row * 64 + c * 8);
            }
        }
#pragma unroll
        for (int ks = 0; ks < 2; ks++)
#pragma unroll
            for (int m = 0; m < 2; m++)
#pragma unroll
                for (int n = 0; n < 4; n++)
                    acc[m][n] = __builtin_amdgcn_mfma_f32_16x16x32_bf16(af[ks][m], bf[ks][n], acc[m][n], 0, 0, 0);
        __syncthreads();
    }

    int cn[4];
#pragma unroll
    for (int n = 0; n < 4; n++) cn[n] = w * 64 + n * 16 + lr;

    if constexpr (MODE == 0) {
        float a1v[4], a2v[4];
#pragma unroll
        for (int n = 0; n < 4; n++) { a1v[n] = ga[cn[n]]; a2v[n] = ga[Dn + cn[n]]; }
#pragma unroll
        for (int m = 0; m < 2; m++)
#pragma unroll
            for (int r = 0; r < 4; r++) {
                int rowl = m * 16 + g * 4 + r;
                float p1 = 0.f, p2 = 0.f;
#pragma unroll
                for (int n = 0; n < 4; n++) {
                    float v = acc[m][n][r];
                    Whout[(size_t)(m0 + rowl) * Dn + cn[n]] = v;
                    p1 += v * a1v[n];
                    p2 += v * a2v[n];
                }
                p1 += __shfl_xor(p1, 1); p2 += __shfl_xor(p2, 1);
                p1 += __shfl_xor(p1, 2); p2 += __shfl_xor(p2, 2);
                p1 += __shfl_xor(p1, 4); p2 += __shfl_xor(p2, 4);
                p1 += __shfl_xor(p1, 8); p2 += __shfl_xor(p2, 8);
                if (lr == 0) { red1[rowl][w] = p1; red2[rowl][w] = p2; }
            }
        __syncthreads();
        if (tid < 32) {
            float t1 = red1[tid][0] + red1[tid][1] + red1[tid][2] + red1[tid][3];
            float t2 = red2[tid][0] + red2[tid][1] + red2[tid][2] + red2[tid][3];
            a1h[m0 + tid] = t1;
            a2h[m0 + tid] = t2;
        }
    } else {
        float bv[4], lgv[4], lbv[4];
#pragma unroll
        for (int n = 0; n < 4; n++) { bv[n] = bias[cn[n]]; lgv[n] = lg[cn[n]]; lbv[n] = lb[cn[n]]; }
#pragma unroll
        for (int m = 0; m < 2; m++)
#pragma unroll
            for (int r = 0; r < 4; r++) {
                int rowl = m * 16 + g * 4 + r;
                float s1 = 0.f, s2 = 0.f;
#pragma unroll
                for (int n = 0; n < 4; n++) {
                    float y = acc[m][n][r] + bv[n] + x[(size_t)(m0 + rowl) * Dn + cn[n]];
                    acc[m][n][r] = y;
                    s1 += y;
                    s2 += y * y;
                }
                s1 += __shfl_xor(s1, 1); s2 += __shfl_xor(s2, 1);
                s1 += __shfl_xor(s1, 2); s2 += __shfl_xor(s2, 2);
                s1 += __shfl_xor(s1, 4); s2 += __shfl_xor(s2, 4);
                s1 += __shfl_xor(s1, 8); s2 += __shfl_xor(s2, 8);
                if (lr == 0) { red1[rowl][w] = s1; red2[rowl][w] = s2; }
            }
        __syncthreads();
#pragma unroll
        for (int m = 0; m < 2; m++)
#pragma unroll
            for (int r = 0; r < 4; r++) {
                int rowl = m * 16 + g * 4 + r;
                float S1 = red1[rowl][0] + red1[rowl][1] + red1[rowl][2] + red1[rowl][3];
                float S2 = red2[rowl][0] + red2[rowl][1] + red2[rowl][2] + red2[rowl][3];
                float mean = S1 * (1.0f / Dn);
                float var = S2 * (1.0f / Dn) - mean * mean;
                float rs = rsqrtf(var + 1e-5f);
#pragma unroll
                for (int n = 0; n < 4; n++) {
                    float o = lgv[n] * (acc[m][n][r] - mean) * rs + lbv[n];
                    size_t idx = (size_t)(m0 + rowl) * Dn + cn[n];
                    x[idx] = o;
                    xb[idx] = f2b(o);
                }
            }
    }
}

// ---------------- GAT band softmax + ELU + residual + LN (wave per row) ----------------
__global__ __launch_bounds__(256) void k_gat_attn_ln(const float* __restrict__ Wh,
                                                     const float* __restrict__ a1h,
                                                     const float* __restrict__ a2h,
                                                     const unsigned char* __restrict__ mask,
                                                     const float* __restrict__ lg,
                                                     const float* __restrict__ lb,
                                                     float* __restrict__ x,
                                                     ushortT* __restrict__ xb) {
    int w = threadIdx.x >> 6, l = threadIdx.x & 63;
    int bs = blockIdx.x * 4 + w;
    int b = bs >> 9, i = bs & 511;
    float e = -1e30f;
    int j = i + l - BANDR;
    if (l < NBn && j >= 0 && j < Sn && mask[bs * NBn + l])
        e = a1h[bs] + a2h[(b << 9) + j];
    float mx = e;
#pragma unroll
    for (int o = 32; o; o >>= 1) mx = fmaxf(mx, __shfl_xor(mx, o));
    float p = (e > -1e29f) ? __expf(e - mx) : 0.0f;
    float sum = p;
#pragma unroll
    for (int o = 32; o; o >>= 1) sum += __shfl_xor(sum, o);
    p *= (1.0f / sum);
    int c4 = l * 4;
    const float* whb = Wh + (size_t)(b << 9) * Dn + c4;
    float gx = 0.f, gy = 0.f, gz = 0.f, gw = 0.f;
#pragma unroll
    for (int o = 0; o < NBn; o++) {
        float wo = __shfl(p, o);
        int jo = i + o - BANDR;
        jo = jo < 0 ? 0 : (jo > Sn - 1 ? Sn - 1 : jo);
        float4 v = *(const float4*)(whb + (size_t)jo * Dn);
        gx += wo * v.x; gy += wo * v.y; gz += wo * v.z; gw += wo * v.w;
    }
    gx = gx > 0.f ? gx : expm1f(gx);
    gy = gy > 0.f ? gy : expm1f(gy);
    gz = gz > 0.f ? gz : expm1f(gz);
    gw = gw > 0.f ? gw : expm1f(gw);
    float4 xv = *(const float4*)(x + (size_t)bs * Dn + c4);
    float y0 = xv.x + gx, y1 = xv.y + gy, y2 = xv.z + gz, y3 = xv.w + gw;
    float s1 = y0 + y1 + y2 + y3;
    float s2 = y0 * y0 + y1 * y1 + y2 * y2 + y3 * y3;
#pragma unroll
    for (int o = 32; o; o >>= 1) {
        s1 += __shfl_xor(s1, o);
        s2 += __shfl_xor(s2, o);
    }
    float mean = s1 * (1.0f / Dn);
    float var = s2 * (1.0f / Dn) - mean * mean;
    float r = rsqrtf(var + 1e-5f);
    float4 lgv = *(const float4*)(lg + c4);
    float4 lbv = *(const float4*)(lb + c4);
    float o0 = lgv.x * (y0 - mean) * r + lbv.x;
    float o1 = lgv.y * (y1 - mean) * r + lbv.y;
    float o2 = lgv.z * (y2 - mean) * r + lbv.z;
    float o3 = lgv.w * (y3 - mean) * r + lbv.w;
    *(float4*)(x + (size_t)bs * Dn + c4) = make_float4(o0, o1, o2, o3);
    us4 ob = {f2b(o0), f2b(o1), f2b(o2), f2b(o3)};
    *(us4*)(xb + (size_t)bs * Dn + c4) = ob;
}

// ---------------- MFMA flash attention v5 (R10 best version) ----------------
__global__ __launch_bounds__(256) void k_attn_mfma(const ushortT* __restrict__ qkv,
                                                   ushortT* __restrict__ ob) {
    __shared__ ushortT Ks[2][64 * 32];
    __shared__ ushortT Vt[2][32 * 64];
    __shared__ ushortT Ps[4][2][16 * 72];
    int tid = threadIdx.x;
    int w = tid >> 6, lane = tid & 63;
    int g = lane >> 4, lr = lane & 15;
    int blk = blockIdx.x;
    int qh = blk & 1, h = (blk >> 1) & 7, b = blk >> 4;
    const ushortT* base = qkv + (size_t)b * Sn * 768;
    const ushortT* kbase = base + 256 + h * 32;
    const ushortT* vbase = base + 512 + h * 32;

    int krow2 = tid >> 3;
    int kc = (tid & 7) ^ (krow2 & 7);
    int kkv = krow2 * 2 + (kc >> 2);
    int kdd = (kc & 3) * 8;
    int vd0 = w * 8;

    int q0 = qh * 256 + w * 64;
    s8v qf[4];
#pragma unroll
    for (int m = 0; m < 4; m++)
        qf[m] = *(const s8v*)(base + (size_t)(q0 + m * 16 + lr) * 768 + h * 32 + g * 8);

    f4v o[4][2];
    float rl[4][4];
#pragma unroll
    for (int m = 0; m < 4; m++) {
        o[m][0] = (f4v){0.f, 0.f, 0.f, 0.f};
        o[m][1] = (f4v){0.f, 0.f, 0.f, 0.f};
#pragma unroll
        for (int r = 0; r < 4; r++) rl[m][r] = 0.f;
    }
    const float scale = 0.17677669529663687f;  // 1/sqrt(32)

    {
        GLDS16(kbase + (size_t)kkv * 768 + kdd, &Ks[0][tid * 8]);
        us4 v0 = *(const us4*)(vbase + (size_t)lane * 768 + vd0);
        us4 v1 = *(const us4*)(vbase + (size_t)lane * 768 + vd0 + 4);
#pragma unroll
        for (int jj = 0; jj < 4; jj++) {
            int d = vd0 + jj;
            Vt[0][d * 64 + (lane ^ ((d & 7) << 3))] = v0[jj];
            int d2 = d + 4;
            Vt[0][d2 * 64 + (lane ^ ((d2 & 7) << 3))] = v1[jj];
        }
    }
    __syncthreads();

    for (int kt = 0; kt < 8; kt++) {
        int cur = kt & 1, nxt = cur ^ 1;
        us4 v0, v1;
        if (kt < 7) {
            GLDS16(kbase + (size_t)((kt + 1) * 64 + kkv) * 768 + kdd, &Ks[nxt][tid * 8]);
            v0 = *(const us4*)(vbase + (size_t)((kt + 1) * 64 + lane) * 768 + vd0);
            v1 = *(const us4*)(vbase + (size_t)((kt + 1) * 64 + lane) * 768 + vd0 + 4);
        }
        s8v kf[4];
#pragma unroll
        for (int n = 0; n < 4; n++) {
            int row2 = n * 8 + (lr >> 1);
            int cc = (((lr & 1) << 2) + g) ^ (row2 & 7);
            kf[n] = *(const s8v*)(&Ks[cur][row2 * 64 + cc * 8]);
        }
        s8v vf[2][2];
#pragma unroll
        for (int cd = 0; cd < 2; cd++)
#pragma unroll
            for (int c2 = 0; c2 < 2; c2++) {
                int d = cd * 16 + lr;
                vf[cd][c2] = *(const s8v*)(&Vt[cur][d * 64 + ((c2 * 32 + g * 8) ^ ((d & 7) << 3))]);
            }
        // pipelined m-loop: QK(m) -> exp(m) -> PV(m-1) -> store(m)
#pragma unroll
        for (int m = 0; m < 4; m++) {
            f4v s[4];
#pragma unroll
            for (int n = 0; n < 4; n++) {
                f4v z = (f4v){0.f, 0.f, 0.f, 0.f};
                s[n] = __builtin_amdgcn_mfma_f32_16x16x32_bf16(qf[m], kf[n], z, 0, 0, 0);
            }
            float pr[4][4];
#pragma unroll
            for (int r = 0; r < 4; r++) {
                pr[0][r] = __expf(fminf(s[0][r] * scale, 60.f));
                pr[1][r] = __expf(fminf(s[1][r] * scale, 60.f));
                pr[2][r] = __expf(fminf(s[2][r] * scale, 60.f));
                pr[3][r] = __expf(fminf(s[3][r] * scale, 60.f));
                rl[m][r] += (pr[0][r] + pr[1][r]) + (pr[2][r] + pr[3][r]);
            }
            if (m > 0) {
                int pb = (m - 1) & 1;
                s8v pf0 = *(const s8v*)(&Ps[w][pb][lr * 72 + g * 8]);
                s8v pf1 = *(const s8v*)(&Ps[w][pb][lr * 72 + 32 + g * 8]);
                o[m - 1][0] = __builtin_amdgcn_mfma_f32_16x16x32_bf16(pf0, vf[0][0], o[m - 1][0], 0, 0, 0);
                o[m - 1][0] = __builtin_amdgcn_mfma_f32_16x16x32_bf16(pf1, vf[0][1], o[m - 1][0], 0, 0, 0);
                o[m - 1][1] = __builtin_amdgcn_mfma_f32_16x16x32_bf16(pf0, vf[1][0], o[m - 1][1], 0, 0, 0);
                o[m - 1][1] = __builtin_amdgcn_mfma_f32_16x16x32_bf16(pf1, vf[1][1], o[m - 1][1], 0, 0, 0);
            }
            int sb = m & 1;
#pragma unroll
            for (int r = 0; r < 4; r++) {
                int rr = g * 4 + r;
                Ps[w][sb][rr * 72 + lr]      = f2b(pr[0][r]);
                Ps[w][sb][rr * 72 + 16 + lr] = f2b(pr[1][r]);
                Ps[w][sb][rr * 72 + 32 + lr] = f2b(pr[2][r]);
                Ps[w][sb][rr * 72 + 48 + lr] = f2b(pr[3][r]);
            }
        }
        {
            s8v pf0 = *(const s8v*)(&Ps[w][1][lr * 72 + g * 8]);
            s8v pf1 = *(const s8v*)(&Ps[w][1][lr * 72 + 32 + g * 8]);
            o[3][0] = __builtin_amdgcn_mfma_f32_16x16x32_bf16(pf0, vf[0][0], o[3][0], 0, 0, 0);
            o[3][0] = __builtin_amdgcn_mfma_f32_16x16x32_bf16(pf1, vf[0][1], o[3][0], 0, 0, 0);
            o[3][1] = __builtin_amdgcn_mfma_f32_16x16x32_bf16(pf0, vf[1][0], o[3][1], 0, 0, 0);
            o[3][1] = __builtin_amdgcn_mfma_f32_16x16x32_bf16(pf1, vf[1][1], o[3][1], 0, 0, 0);
        }
        if (kt < 7) {
#pragma unroll
            for (int jj = 0; jj < 4; jj++) {
                int d = vd0 + jj;
                Vt[nxt][d * 64 + (lane ^ ((d & 7) << 3))] = v0[jj];
                int d2 = d + 4;
                Vt[nxt][d2 * 64 + (lane ^ ((d2 & 7) << 3))] = v1[jj];
            }
        }
        __syncthreads();
    }
#pragma unroll
    for (int m = 0; m < 4; m++) {
#pragma unroll
        for (int r = 0; r < 4; r++) {
            float t = rl[m][r];
            t += __shfl_xor(t, 1);
            t += __shfl_xor(t, 2);
            t += __shfl_xor(t, 4);
            t += __shfl_xor(t, 8);
            float inv = 1.0f / t;
            int qr = q0 + m * 16 + g * 4 + r;
            size_t obase = ((size_t)(b * Sn + qr)) * Dn + h * 32;
            ob[obase + lr] = f2b(o[m][0][r] * inv);
            ob[obase + 16 + lr] = f2b(o[m][1][r] * inv);
        }
    }
}

// ---------------- fused mean-pool + classifier ----------------
__global__ void k_pool_cls(const float* __restrict__ x, const float* __restrict__ w1,
                           const float* __restrict__ b1, const float* __restrict__ w2,
                           const float* __restrict__ b2, float* __restrict__ out) {
    int b = blockIdx.x;
    int t = threadIdx.x;  // 256
    __shared__ float pooled[Dn];
    __shared__ float hbuf[128];
    float s = 0.f;
    const float* xp = x + (size_t)(b << 9) * Dn + t;
    for (int sx = 0; sx < Sn; sx++) s += xp[(size_t)sx * Dn];
    pooled[t] = s * (1.0f / Sn);
    __syncthreads();
    if (t < 128) {
        float a = b1[t];
        for (int k = 0; k < Dn; k++) a += pooled[k] * w1[t * Dn + k];
        hbuf[t] = fmaxf(a, 0.0f);
    }
    __syncthreads();
    if (t < NCLSn) {
        float a2 = b2[t];
        for (int k = 0; k < 128; k++) a2 += hbuf[k] * w2[t * 128 + k];
        out[b * NCLSn + t] = a2;
    }
}

extern "C" void kernel_launch(void* const* d_in, const int* in_sizes, int n_in,
                              void* d_out, int out_size, void* d_ws, size_t ws_size,
                              hipStream_t stream) {
    const int* cat = (const int*)d_in[0];
    const float* cnt = (const float*)d_in[1];
    const float* emb0 = (const float*)d_in[2];
    const float* emb1 = (const float*)d_in[3];
    const float* emb2 = (const float*)d_in[4];
    const float* cnt_W = (const float*)d_in[5];
    const float* cnt_b = (const float*)d_in[6];
    const float* pos_enc = (const float*)d_in[7];
    const float* gat_W = (const float*)d_in[8];
    const float* gat_a = (const float*)d_in[9];
    const float* qkv_W = (const float*)d_in[10];
    const float* qkv_b = (const float*)d_in[11];
    const float* outp_W = (const float*)d_in[12];
    const float* outp_b = (const float*)d_in[13];
    const float* ff1_W = (const float*)d_in[14];
    const float* ff1_b = (const float*)d_in[15];
    const float* ff2_W = (const float*)d_in[16];
    const float* ff2_b = (const float*)d_in[17];
    const float* ln_g = (const float*)d_in[18];
    const float* ln_b = (const float*)d_in[19];
    const float* cls1_W = (const float*)d_in[20];
    const float* cls1_b = (const float*)d_in[21];
    const float* cls2_W = (const float*)d_in[22];
    const float* cls2_b = (const float*)d_in[23];
    float* out = (float*)d_out;

    // workspace layout
    char* wp = (char*)d_ws;
    float* x = (float*)wp;        wp += (size_t)Mn * Dn * 4;
    float* tmpf = (float*)wp;     wp += (size_t)Mn * Dn * 4;
    ushortT* xb = (ushortT*)wp;   wp += (size_t)Mn * Dn * 2;
    ushortT* qkvb = (ushortT*)wp; wp += (size_t)Mn * 3 * Dn * 2;
    ushortT* ffb = qkvb;  // alias: qkv dead before ff1 writes
    ushortT* obb = (ushortT*)wp;  wp += (size_t)Mn * Dn * 2;
    float* a1h = (float*)wp;      wp += (size_t)Mn * 4;
    float* a2h = (float*)wp;      wp += (size_t)Mn * 4;
    unsigned char* mask = (unsigned char*)wp; wp += (size_t)Mn * NBn;
    ushortT* gatWb = (ushortT*)wp;  wp += (size_t)Ln * Dn * Dn * 2;
    ushortT* qkvWb = (ushortT*)wp;  wp += (size_t)Ln * 3 * Dn * Dn * 2;
    ushortT* outpWb = (ushortT*)wp; wp += (size_t)Ln * Dn * Dn * 2;
    ushortT* ff1Wb = (ushortT*)wp;  wp += (size_t)Ln * FFn * Dn * 2;
    ushortT* ff2Wb = (ushortT*)wp;  wp += (size_t)Ln * Dn * FFn * 2;

    // allow 72 KB dynamic LDS for the row-GEMM (gfx950: 160 KB/WG)
    const int rowLds = (4096 + 32768) * (int)sizeof(ushortT);  // 73728 B
    (void)hipFuncSetAttribute((const void*)k_gemm_row<0>,
                              hipFuncAttributeMaxDynamicSharedMemorySize, rowLds);
    (void)hipFuncSetAttribute((const void*)k_gemm_row<1>,
                              hipFuncAttributeMaxDynamicSharedMemorySize, rowLds);

    k_f2b_all<<<1536, 256, 0, stream>>>(qkv_W, outp_W, ff1_W, ff2_W, gat_W,
                                        qkvWb, outpWb, ff1Wb, ff2Wb, gatWb);
    k_embed_mask<<<Mn + 1216, 256, 0, stream>>>(cat, cnt, emb0, emb1, emb2, cnt_W, cnt_b,
                                                pos_enc, x, xb, mask);

    for (int l = 0; l < Ln; l++) {
        // GAT: Wh = x @ gat_W[l] fused with score dots -> tmpf, a1h, a2h
        k_gemm_row<0><<<Mn / 32, 256, rowLds, stream>>>(
            xb, gatWb + (size_t)l * Dn * Dn, nullptr,
            gat_a + (size_t)l * 2 * Dn, a1h, a2h, tmpf,
            nullptr, nullptr, nullptr, nullptr, Dn);
        k_gat_attn_ln<<<Mn / 4, 256, 0, stream>>>(tmpf, a1h, a2h, mask,
                                                  ln_g + (l * 3 + 0) * Dn, ln_b + (l * 3 + 0) * Dn, x, xb);
        // MHA
        k_gemm_mfma<0><<<dim3(3 * Dn / 128, Mn / 128), 256, 0, stream>>>(
            xb, qkvWb + (size_t)l * 3 * Dn * Dn, qkv_b + l * 3 * Dn, qkvb, Mn, 3 * Dn, Dn);
        k_attn_mfma<<<Bn * Hn * 2, 256, 0, stream>>>(qkvb, obb);
        // out-proj fused with residual + LN
        k_gemm_row<1><<<Mn / 32, 256, rowLds, stream>>>(
            obb, outpWb + (size_t)l * Dn * Dn, outp_b + l * Dn,
            nullptr, nullptr, nullptr, nullptr,
            ln_g + (l * 3 + 1) * Dn, ln_b + (l * 3 + 1) * Dn, x, xb, Dn);
        // FFN
        k_gemm_mfma<1><<<dim3(FFn / 128, Mn / 128), 256, 0, stream>>>(
            xb, ff1Wb + (size_t)l * FFn * Dn, ff1_b + l * FFn, ffb, Mn, FFn, Dn);
        k_gemm_row<1><<<Mn / 32, 256, rowLds, stream>>>(
            ffb, ff2Wb + (size_t)l * Dn * FFn, ff2_b + l * Dn,
            nullptr, nullptr, nullptr, nullptr,
            ln_g + (l * 3 + 2) * Dn, ln_b + (l * 3 + 2) * Dn, x, xb, FFn);
    }

    k_pool_cls<<<Bn, 256, 0, stream>>>(x, cls1_W, cls1_b, cls2_W, cls2_b, out);
}